// Round 3
// baseline (277.280 us; speedup 1.0000x reference)
//
#include <hip/hip_runtime.h>

// PointNetKnnInterpolator on MI355X (gfx950).
// R13: precompute the x-dependent half of the net per x-point.
//   Z  = x@Wsa[0:64]        + b1a   (20000x64 f32, prep kernel)
//   Z1 = relu(x)@W0a[0:64]  + b0a
// Per data row: mm3 = gather Z[xi]  + diff@Wsa[64:67]   (rank-3 MFMA)
//               mm1 = gather Z1[xi] + relu(diff)@W0a[64:67]
// -> 96->64 MFMAs/pair, 48->32 frag ds_reads, x16 gather+relu VALU gone,
//    chain head becomes pure loads (accumulator C-init from gathered Z).
// Epilogue: in-register f16-packed 3-stage shfl_xor(1/2/4) max (same RTN f16
// numerics as the verified ebuf path) -- no LDS round trip, no fences, no
// bank conflicts. Biases: b1a/b0a inside Z/Z1 (f32); b0b = mm4 acc init from
// LDS; b1b commutes with max, added at store. Tail fix: atomic work-stealing
// (counter in d_ws, zeroed by prep; round 1 static to avoid the herd).
// R10-R12 falsified: MFMA count, gather latency, LDS BW, per-wave ILP.

typedef _Float16 f16x8 __attribute__((ext_vector_type(8)));
typedef _Float16 f16x4 __attribute__((ext_vector_type(4)));
typedef float    f32x4 __attribute__((ext_vector_type(4)));

constexpr int NX     = 20000;
constexpr int NROWS  = 50000 * 8;    // NY * K
constexpr int NTILES = NROWS / 16;   // 25000
constexpr int NPAIRS = NTILES / 2;   // 12500
constexpr int NFRAG  = 32;           // W0a_s2 4 | Wsa_s2 4 | W1a 8 | W0b 8 | W1b 8
constexpr int BW     = 8;            // waves per block
constexpr int BLOCK  = 64 * BW;      // 512
constexpr int NXT    = NX / 16;      // 1250 prep tiles (exact)

// d_ws layout (floats): Z[NX*64] | Z1[NX*64] | steal counter (uint)
#define Z1_OFF  ((size_t)NX * 64)
#define CTR_OFF ((size_t)NX * 128)

// ---------------- prep: Z / Z1 GEMM + counter zero ----------------
__global__ __launch_bounds__(BLOCK)
void prep_z(const float* __restrict__ x,
            const float* __restrict__ W0a, const float* __restrict__ b0a,
            const float* __restrict__ Wsa, const float* __restrict__ b1a,
            float* __restrict__ ws)
{
    __shared__ __align__(16) _Float16 wfrag[16 * 64 * 8];   // 16 KiB
    const int tid = threadIdx.x;
    // frags [0..7] = W0a rows 0..63 (for Z1), [8..15] = Wsa rows 0..63 (for Z)
    for (int p = tid; p < 16 * 64; p += BLOCK) {
        const int f = p >> 6, l = p & 63;
        const int q = l >> 4, n0 = l & 15;
        const int grp = f >> 3, fl = f & 7, s = fl >> 2, t = fl & 3;
        const int col = t * 16 + n0;
        const float* W = grp ? Wsa : W0a;
        f16x8 v;
#pragma unroll
        for (int j = 0; j < 8; ++j) {
            const int k = 32 * s + 8 * q + j;           // < 64
            v[j] = (_Float16)W[k * 64 + col];
        }
        *(f16x8*)&wfrag[p * 8] = v;
    }
    __syncthreads();

    const int lane = tid & 63, wv = tid >> 6;
    const int n0 = lane & 15, q = lane >> 4;
    const int tile = blockIdx.x * BW + wv;
#define PWF(fid) (*(const f16x8*)&wfrag[(((fid) * 64) + lane) * 8])
    if (tile < NXT) {
        const float* xr = x + (long)(tile * 16 + n0) * 64 + 8 * q;
        f16x8 xb[2], xrl[2];
#pragma unroll
        for (int s = 0; s < 2; ++s) {
            f32x4 a = *(const f32x4*)(xr + 32 * s);
            f32x4 b = *(const f32x4*)(xr + 32 * s + 4);
#pragma unroll
            for (int e = 0; e < 4; ++e) {
                xb[s][e]     = (_Float16)a[e];
                xb[s][4 + e] = (_Float16)b[e];
            }
#pragma unroll
            for (int e = 0; e < 8; ++e)
                xrl[s][e] = xb[s][e] > (_Float16)0 ? xb[s][e] : (_Float16)0;
        }
        f32x4 AZ[4], AZ1[4];
#pragma unroll
        for (int t = 0; t < 4; ++t) {
            AZ[t]  = *(const f32x4*)(b1a + 16 * t + 4 * q);   // bias folded in, f32
            AZ1[t] = *(const f32x4*)(b0a + 16 * t + 4 * q);
        }
#pragma unroll
        for (int s = 0; s < 2; ++s)
#pragma unroll
            for (int t = 0; t < 4; ++t) {
                AZ[t]  = __builtin_amdgcn_mfma_f32_16x16x32_f16(PWF(8 + s * 4 + t), xb[s],  AZ[t],  0, 0, 0);
                AZ1[t] = __builtin_amdgcn_mfma_f32_16x16x32_f16(PWF(0 + s * 4 + t), xrl[s], AZ1[t], 0, 0, 0);
            }
        float* zr  = ws + (long)(tile * 16 + n0) * 64;
        float* z1r = ws + Z1_OFF + (long)(tile * 16 + n0) * 64;
#pragma unroll
        for (int t = 0; t < 4; ++t) {
            *(f32x4*)(zr  + 16 * t + 4 * q) = AZ[t];    // feat = 16t+4q+r (C-layout)
            *(f32x4*)(z1r + 16 * t + 4 * q) = AZ1[t];
        }
    }
#undef PWF
    if (blockIdx.x == 0 && tid == 0)
        *((unsigned*)(ws + CTR_OFF)) = 0u;              // steal counter
}

// relu + repack accumulator (C-layout) into the two K=64 B-fragments.
// frag s element j  <->  acc[t=2s+(j>>2)][r=j&3]   (matches PHI weight layout)
static __device__ __forceinline__ void pack_relu(const f32x4* A, f16x8* bf) {
#pragma unroll
    for (int s = 0; s < 2; ++s) {
        f16x8 r;
#pragma unroll
        for (int e = 0; e < 8; ++e) {
            float v = A[2 * s + (e >> 2)][e & 3];
            r[e] = (_Float16)(v > 0.0f ? v : 0.0f);
        }
        bf[s] = r;
    }
}

__global__ __launch_bounds__(BLOCK, 4)
void pointnet_fused(const float* __restrict__ ws,
                    const float* __restrict__ pos_x,
                    const float* __restrict__ pos_y,
                    const int*   __restrict__ x_idx,
                    const float* __restrict__ W0a,
                    const float* __restrict__ W1a,
                    const float* __restrict__ Wsa,
                    const float* __restrict__ W0b, const float* __restrict__ b0b,
                    const float* __restrict__ W1b, const float* __restrict__ b1b,
                    float* __restrict__ out)
{
    __shared__ __align__(16) _Float16 bfrag[NFRAG * 64 * 8];   // 32 KiB
    __shared__ __align__(16) float    bias3f[64];              // b0b (mm4 acc init)
    __shared__ __align__(16) float    bias5f[64];              // b1b (post-max add)

    const int tid = threadIdx.x;

    // ---- fill weight fragments ----
    // [0..3] W0a rows 64..66 (s2) | [4..7] Wsa rows 64..66 (s2)
    // [8..15] W1a PHI | [16..23] W0b PHI | [24..31] W1b PHI
    for (int p = tid; p < NFRAG * 64; p += BLOCK) {
        const int f = p >> 6, l = p & 63;
        const int q = l >> 4, n0 = l & 15;
        f16x8 v;
        if (f < 8) {
            const int t = f & 3;
            const int col = t * 16 + n0;
            const float* W = (f < 4) ? W0a : Wsa;
#pragma unroll
            for (int j = 0; j < 8; ++j) {
                const int k = 64 + 8 * q + j;
                v[j] = (_Float16)((k < 67) ? W[k * 64 + col] : 0.0f);
            }
        } else {
            const int fl = (f - 8) & 7, s = fl >> 2, t = fl & 3;
            const int col = t * 16 + n0;
            const float* W = (f < 16) ? W1a : (f < 24) ? W0b : W1b;
#pragma unroll
            for (int j = 0; j < 8; ++j) {
                const int row = 32 * s + 16 * (j >> 2) + 4 * q + (j & 3);  // PHI(k)
                v[j] = (_Float16)W[row * 64 + col];
            }
        }
        *(f16x8*)&bfrag[p * 8] = v;
    }
    if (tid < 64)       bias3f[tid]      = b0b[tid];
    else if (tid < 128) bias5f[tid - 64] = b1b[tid - 64];
    __syncthreads();

    const int lane = tid & 63;
    const int wv   = tid >> 6;
    const int n0   = lane & 15;   // B col = data row (dr) / C-layout col
    const int q    = lane >> 4;

    const float* Zb  = ws;
    const float* Z1b = ws + Z1_OFF;
    unsigned* ctr = (unsigned*)(ws + CTR_OFF);

    const unsigned gwave  = blockIdx.x * BW + wv;
    const unsigned nwaves = gridDim.x * BW;   // 4096

#define WFRAG(fid) (*(const f16x8*)&bfrag[(((fid) * 64) + lane) * 8])

    unsigned pcur = gwave;                    // round 1 static (no herd)
    while (pcur < NPAIRS) {
        unsigned pnxt = 0;
        if (lane == 0) pnxt = nwaves + atomicAdd(ctr, 1u);   // steal next pair

        const int tA = (int)pcur * 2;

        // ---- gather: Z/Z1 as accumulator C-init + diff frag ----
        f32x4 A2[2][4], A1[2][4];
        f16x8 hd[2], hdr[2];
#pragma unroll
        for (int u = 0; u < 2; ++u) {
            const int row = (tA + u) * 16 + n0;
            const int xi  = x_idx[row];
            const float* zp  = Zb  + (long)xi * 64 + 4 * q;
            const float* z1p = Z1b + (long)xi * 64 + 4 * q;
#pragma unroll
            for (int t = 0; t < 4; ++t) {
                A2[u][t] = *(const f32x4*)(zp  + 16 * t);   // Z  (+b1a)
                A1[u][t] = *(const f32x4*)(z1p + 16 * t);   // Z1 (+b0a)
            }
            f16x8 z = {};
            hd[u] = z;
            if (q == 0) {
                const int yi = row >> 3;
#pragma unroll
                for (int j = 0; j < 3; ++j)
                    hd[u][j] = (_Float16)(pos_x[xi * 3 + j] - pos_y[yi * 3 + j]);
            }
#pragma unroll
            for (int j = 0; j < 8; ++j)
                hdr[u][j] = hd[u][j] > (_Float16)0 ? hd[u][j] : (_Float16)0;
        }

        // ---- mm3 (diff@Wsa_s2 into Z-init) & mm1 (relu(diff)@W0a_s2 into Z1-init) ----
#pragma unroll
        for (int u = 0; u < 2; ++u)
#pragma unroll
            for (int t = 0; t < 4; ++t) {
                A2[u][t] = __builtin_amdgcn_mfma_f32_16x16x32_f16(WFRAG(4 + t), hd[u],  A2[u][t], 0, 0, 0);
                A1[u][t] = __builtin_amdgcn_mfma_f32_16x16x32_f16(WFRAG(0 + t), hdr[u], A1[u][t], 0, 0, 0);
            }

        // ---- mm2: A2 += (relu(net) @ W1a)^T ----
        f16x8 bf[2][2];
#pragma unroll
        for (int u = 0; u < 2; ++u) pack_relu(A1[u], bf[u]);
#pragma unroll
        for (int s = 0; s < 2; ++s)
#pragma unroll
            for (int t = 0; t < 4; ++t) {
                const f16x8 w = WFRAG(8 + s * 4 + t);
                A2[0][t] = __builtin_amdgcn_mfma_f32_16x16x32_f16(w, bf[0][s], A2[0][t], 0, 0, 0);
                A2[1][t] = __builtin_amdgcn_mfma_f32_16x16x32_f16(w, bf[1][s], A2[1][t], 0, 0, 0);
            }

        // ---- mm4: A1 := b0b + (relu(h2) @ W0b)^T   (A1 storage reused) ----
#pragma unroll
        for (int u = 0; u < 2; ++u) pack_relu(A2[u], bf[u]);
#pragma unroll
        for (int u = 0; u < 2; ++u)
#pragma unroll
            for (int t = 0; t < 4; ++t) A1[u][t] = *(const f32x4*)&bias3f[16 * t + 4 * q];
#pragma unroll
        for (int s = 0; s < 2; ++s)
#pragma unroll
            for (int t = 0; t < 4; ++t) {
                const f16x8 w = WFRAG(16 + s * 4 + t);
                A1[0][t] = __builtin_amdgcn_mfma_f32_16x16x32_f16(w, bf[0][s], A1[0][t], 0, 0, 0);
                A1[1][t] = __builtin_amdgcn_mfma_f32_16x16x32_f16(w, bf[1][s], A1[1][t], 0, 0, 0);
            }

        // ---- mm5: A2 += (relu(net2) @ W1b)^T  -> h3^T ----
#pragma unroll
        for (int u = 0; u < 2; ++u) pack_relu(A1[u], bf[u]);
#pragma unroll
        for (int s = 0; s < 2; ++s)
#pragma unroll
            for (int t = 0; t < 4; ++t) {
                const f16x8 w = WFRAG(24 + s * 4 + t);
                A2[0][t] = __builtin_amdgcn_mfma_f32_16x16x32_f16(w, bf[0][s], A2[0][t], 0, 0, 0);
                A2[1][t] = __builtin_amdgcn_mfma_f32_16x16x32_f16(w, bf[1][s], A2[1][t], 0, 0, 0);
            }

        // ---- epilogue: in-register f16 max over dr (lane bits 0..2), no LDS ----
#pragma unroll
        for (int u = 0; u < 2; ++u) {
            union U { f16x8 h; int i[4]; };
            U pa, pb;
#pragma unroll
            for (int e = 0; e < 8; ++e) {
                pa.h[e] = (_Float16)A2[u][(e >> 2)][e & 3];       // feats t=0,1
                pb.h[e] = (_Float16)A2[u][2 + (e >> 2)][e & 3];   // feats t=2,3
            }
#pragma unroll
            for (int st = 0; st < 3; ++st) {
                const int m = 1 << st;                            // xor 1,2,4
                U qa, qb;
#pragma unroll
                for (int d = 0; d < 4; ++d) {
                    qa.i[d] = __shfl_xor(pa.i[d], m, 64);
                    qb.i[d] = __shfl_xor(pb.i[d], m, 64);
                }
#pragma unroll
                for (int e = 0; e < 8; ++e) {
                    pa.h[e] = pa.h[e] > qa.h[e] ? pa.h[e] : qa.h[e];
                    pb.h[e] = pb.h[e] > qb.h[e] ? pb.h[e] : qb.h[e];
                }
            }
            if ((n0 & 7) == 0) {
                const int y = (tA + u) * 2 + (n0 >> 3);
                float* op = out + (long)y * 64;
#pragma unroll
                for (int t = 0; t < 4; ++t) {
                    const f32x4 bb = *(const f32x4*)&bias5f[16 * t + 4 * q];
                    const int e0 = (t & 1) * 4;
                    float4 vst;
                    if (t < 2) vst = {(float)pa.h[e0 + 0] + bb[0], (float)pa.h[e0 + 1] + bb[1],
                                      (float)pa.h[e0 + 2] + bb[2], (float)pa.h[e0 + 3] + bb[3]};
                    else       vst = {(float)pb.h[e0 + 0] + bb[0], (float)pb.h[e0 + 1] + bb[1],
                                      (float)pb.h[e0 + 2] + bb[2], (float)pb.h[e0 + 3] + bb[3]};
                    *(float4*)(op + 16 * t + 4 * q) = vst;
                }
            }
        }

        pnxt = (unsigned)__shfl((int)pnxt, 0);   // late use: atomic latency hidden
        pcur = pnxt;
    }
#undef WFRAG
}

extern "C" void kernel_launch(void* const* d_in, const int* in_sizes, int n_in,
                              void* d_out, int out_size, void* d_ws, size_t ws_size,
                              hipStream_t stream) {
    (void)in_sizes; (void)n_in; (void)ws_size; (void)out_size;
    float* ws = (float*)d_ws;

    prep_z<<<(NXT + BW - 1) / BW, BLOCK, 0, stream>>>(
        (const float*)d_in[0],                           // x
        (const float*)d_in[5], (const float*)d_in[6],    // W0a, b0a
        (const float*)d_in[9], (const float*)d_in[8],    // Wsa, b1a
        ws);

    pointnet_fused<<<512, BLOCK, 0, stream>>>(
        ws,
        (const float*)d_in[1],   // pos_x
        (const float*)d_in[2],   // pos_y
        (const int*)  d_in[3],   // x_idx
        (const float*)d_in[5],   // W0a (rows 64..66)
        (const float*)d_in[7],   // W1a
        (const float*)d_in[9],   // Wsa (rows 64..66)
        (const float*)d_in[10], (const float*)d_in[11],  // W0b, b0b
        (const float*)d_in[12], (const float*)d_in[13],  // W1b, b1b
        (float*)d_out);
}